// Round 17
// baseline (975.730 us; speedup 1.0000x reference)
//
#include <hip/hip_runtime.h>
#include <math.h>

#define NSPLIT 64      // spans per batch
#define SPAN 64        // rows per attn block
#define TROWS 4        // rows per tile
#define NTIL 16        // SPAN/TROWS

__device__ __forceinline__ float wsum(float v) {
#pragma unroll
  for (int off = 32; off >= 1; off >>= 1) v += __shfl_xor(v, off, 64);
  return v;
}
__device__ __forceinline__ float dot4(const float4 a, const float4 b) {
  return a.x * b.x + a.y * b.y + a.z * b.z + a.w * b.w;
}

// ---------------- proj1: c_q / c_kv_new / k_rope_new from hidden (K=2048) ----
__global__ __launch_bounds__(256) void proj1_kernel(
    const float* __restrict__ hidden, const float* __restrict__ W_dq,
    const float* __restrict__ W_dkv, const float* __restrict__ W_kr,
    float* __restrict__ ws_cq, float* __restrict__ out_ckv,
    float* __restrict__ out_kr) {
  const int wave = threadIdx.x >> 6;
  const int lane = threadIdx.x & 63;
  const int jbase = (blockIdx.x * 4 + wave) * 2;  // 2624 cols total
  const float* w0;
  if (jbase < 512)       w0 = W_dq  + (size_t)jbase * 2048;
  else if (jbase < 2560) w0 = W_dkv + (size_t)(jbase - 512) * 2048;
  else                   w0 = W_kr  + (size_t)(jbase - 2560) * 2048;
  const float* w1 = w0 + 2048;

  __shared__ float wlds[4][2][2048];  // 64 KB

#pragma unroll
  for (int m = 0; m < 8; ++m) {
    __builtin_amdgcn_global_load_lds(
        (const __attribute__((address_space(1))) void*)(w0 + (m << 8) + (lane << 2)),
        (__attribute__((address_space(3))) void*)&wlds[wave][0][m << 8], 16, 0, 0);
    __builtin_amdgcn_global_load_lds(
        (const __attribute__((address_space(1))) void*)(w1 + (m << 8) + (lane << 2)),
        (__attribute__((address_space(3))) void*)&wlds[wave][1][m << 8], 16, 0, 0);
  }
  __syncthreads();   // drains vmcnt; weights in LDS

  float acc0[32], acc1[32];
#pragma unroll
  for (int i = 0; i < 32; ++i) { acc0[i] = 0.f; acc1[i] = 0.f; }

#pragma unroll 1
  for (int m = 0; m < 8; ++m) {
    const int k = (lane << 2) + (m << 8);
    const float4 wa = *(const float4*)&wlds[wave][0][k];
    const float4 wb = *(const float4*)&wlds[wave][1][k];
#pragma unroll
    for (int i = 0; i < 32; ++i) {
      const float4 a = *(const float4*)(hidden + i * 2048 + k);
      acc0[i] += dot4(a, wa);
      acc1[i] += dot4(a, wb);
    }
  }
#pragma unroll
  for (int i = 0; i < 32; ++i) { acc0[i] = wsum(acc0[i]); acc1[i] = wsum(acc1[i]); }

  if (jbase >= 2560) {  // RoPE on k_rope_new, position = t
    const int r0 = jbase - 2560;  // even
    const float inv = powf(10000.f, -(float)r0 / 64.f);
    float cs[4], sn[4];
#pragma unroll
    for (int t = 0; t < 4; ++t) { cs[t] = cosf((float)t * inv); sn[t] = sinf((float)t * inv); }
#pragma unroll
    for (int i = 0; i < 32; ++i) {
      const int t = i & 3;
      const float x0 = acc0[i], x1 = acc1[i];
      acc0[i] = x0 * cs[t] - x1 * sn[t];
      acc1[i] = x0 * sn[t] + x1 * cs[t];
    }
  }

  float myval = 0.f;
#pragma unroll
  for (int i = 0; i < 32; ++i) {
    myval = (lane == i)      ? acc0[i] : myval;
    myval = (lane == i + 32) ? acc1[i] : myval;
  }
  const int mi = lane & 31;               // row (b*4+t)
  const int col = jbase + (lane >> 5);
  const int b = mi >> 2, t = mi & 3;
  if (col < 512)
    ws_cq[mi * 512 + col] = myval;
  else if (col < 2560)
    out_ckv[((size_t)(b * 4096 + 4092 + t)) * 2048 + (col - 512)] = myval;
  else
    out_kr[((size_t)(b * 4096 + 4092 + t)) * 64 + (col - 2560)] = myval;
}

// ---------------- proj2: q_c / q_r (+RoPE) from c_q (K=512) ------------------
__global__ __launch_bounds__(256) void proj2_kernel(
    const float* __restrict__ cq, const float* __restrict__ W_uq,
    const float* __restrict__ W_qr, float* __restrict__ ws_qc,
    float* __restrict__ ws_qr) {
  const int wave = threadIdx.x >> 6;
  const int lane = threadIdx.x & 63;
  const int jbase = (blockIdx.x * 4 + wave) * 2;  // 3072 cols total
  const float* w0 = (jbase < 2048) ? (W_uq + (size_t)jbase * 512)
                                   : (W_qr + (size_t)(jbase - 2048) * 512);
  const float* w1 = w0 + 512;

  __shared__ float wlds[4][2][512];  // 16 KB

#pragma unroll
  for (int m = 0; m < 2; ++m) {
    __builtin_amdgcn_global_load_lds(
        (const __attribute__((address_space(1))) void*)(w0 + (m << 8) + (lane << 2)),
        (__attribute__((address_space(3))) void*)&wlds[wave][0][m << 8], 16, 0, 0);
    __builtin_amdgcn_global_load_lds(
        (const __attribute__((address_space(1))) void*)(w1 + (m << 8) + (lane << 2)),
        (__attribute__((address_space(3))) void*)&wlds[wave][1][m << 8], 16, 0, 0);
  }
  __syncthreads();

  float acc0[32], acc1[32];
#pragma unroll
  for (int i = 0; i < 32; ++i) { acc0[i] = 0.f; acc1[i] = 0.f; }

#pragma unroll 1
  for (int m = 0; m < 2; ++m) {
    const int k = (lane << 2) + (m << 8);
    const float4 wa = *(const float4*)&wlds[wave][0][k];
    const float4 wb = *(const float4*)&wlds[wave][1][k];
#pragma unroll
    for (int i = 0; i < 32; ++i) {
      const float4 a = *(const float4*)(cq + i * 512 + k);
      acc0[i] += dot4(a, wa);
      acc1[i] += dot4(a, wb);
    }
  }
#pragma unroll
  for (int i = 0; i < 32; ++i) { acc0[i] = wsum(acc0[i]); acc1[i] = wsum(acc1[i]); }

  if (jbase >= 2048) {  // RoPE on q_r, position = t
    const int r0 = (jbase - 2048) & 63;  // even
    const float inv = powf(10000.f, -(float)r0 / 64.f);
    float cs[4], sn[4];
#pragma unroll
    for (int t = 0; t < 4; ++t) { cs[t] = cosf((float)t * inv); sn[t] = sinf((float)t * inv); }
#pragma unroll
    for (int i = 0; i < 32; ++i) {
      const int t = i & 3;
      const float x0 = acc0[i], x1 = acc1[i];
      acc0[i] = x0 * cs[t] - x1 * sn[t];
      acc1[i] = x0 * sn[t] + x1 * cs[t];
    }
  }

  float myval = 0.f;
#pragma unroll
  for (int i = 0; i < 32; ++i) {
    myval = (lane == i)      ? acc0[i] : myval;
    myval = (lane == i + 32) ? acc1[i] : myval;
  }
  const int mi = lane & 31;
  const int col = jbase + (lane >> 5);
  if (col < 2048) ws_qc[mi * 2048 + col] = myval;
  else            ws_qr[mi * 1024 + (col - 2048)] = myval;
}

// ---------------- rope scores: rope[b][h*4+t][s] = q_r . k_rope  -------------
__global__ __launch_bounds__(256) void rope_kernel(
    const float* __restrict__ kr_past, float* __restrict__ out_kr,
    const float* __restrict__ qr_g, float* __restrict__ rope) {
  const int chunk = blockIdx.x;  // 64 keys per chunk
  const int b = blockIdx.y;
  const int tid = threadIdx.x;
  const int wave = tid >> 6;
  const int lane = tid & 63;
  const int s0 = chunk * 64;

  __shared__ float krt[64][68];
  __shared__ float sc[64][65];

#pragma unroll
  for (int u = 0; u < 4; ++u) {
    const int fi = tid + u * 256;
    const int row = fi >> 4;
    const int c4  = (fi & 15) << 2;
    const int s = s0 + row;
    float4 v;
    if (s < 4092) {
      v = *(const float4*)(kr_past + ((size_t)b * 4092 + s) * 64 + c4);
      *(float4*)(out_kr + ((size_t)(b * 4096 + s)) * 64 + c4) = v;
    } else {
      v = *(const float4*)(out_kr + ((size_t)(b * 4096 + s)) * 64 + c4);
    }
    *(float4*)&krt[row][c4] = v;
  }

  float4 q[16];
  {
    const float* qrp = qr_g + ((size_t)(b * 4 + (lane & 3))) * 1024 + (lane >> 2) * 64;
#pragma unroll
    for (int m = 0; m < 16; ++m) q[m] = *(const float4*)(qrp + (m << 2));
  }
  __syncthreads();

#pragma unroll 1
  for (int j = 0; j < 16; ++j) {
    const int sl = wave * 16 + j;
    float sum = 0.f;
#pragma unroll
    for (int r = 0; r < 16; ++r) {
      const float4 kv4 = *(const float4*)&krt[sl][r << 2];
      sum += dot4(q[r], kv4);
    }
    sc[lane][sl] = sum;
  }
  __syncthreads();

#pragma unroll
  for (int u = 0; u < 16; ++u) {
    const int e = tid + u * 256;
    const int ht = e >> 6, sl = e & 63;
    rope[((size_t)b * 64 + ht) * 4096 + s0 + sl] = sc[ht][sl];
  }
}

// ---------------- flash attention, whole-row blocks + fused c_kv copy --------
// Block = (span of 64 rows, b), ALL 16 heads. Reads/writes are contiguous
// 8KB row streams (gload_lds linear, 1KB per instruction). Wave = query t and
// staging row; lane = (h = lane>>2, q = lane&3) owning quarter q*32..q*32+31
// of head h. Q quarter in 8 rotated float4 regs (indices compile-time; the
// (lane+i)&7 rotation makes every 16-lane LDS phase hit distinct bank-slots).
// Score: per-key quarter-dot + 2-shfl group reduce. Softmax per 4-lane group.
// PV: p shared via shfl_xor butterfly; rows visited in lane-local order q^j.
__global__ __launch_bounds__(256) void attn_kernel(
    const float* __restrict__ ckv_past, float* __restrict__ out_ckv,
    const float* __restrict__ qc_g, const float* __restrict__ rope,
    float* __restrict__ part_acc, float* __restrict__ part_ml) {
  const int sp = blockIdx.x;           // 0..63
  const int b  = blockIdx.y;
  const int tid  = threadIdx.x;
  const int wv   = tid >> 6;
  const int lane = tid & 63;
  const int h = lane >> 2;
  const int q = lane & 3;
  const int t = wv;

  __shared__ float kv[2][TROWS][2048];  // 64 KB

  const int s_begin = sp * SPAN;
  const int lim = 4092 + t;            // inclusive causal limit

  // Q quarter, rotated: qv[i] = dims q*32 + ((lane+i)&7)*4 ..+3
  float4 qv[8];
  {
    const float* qp = qc_g + ((size_t)(b * 4 + t)) * 2048 + h * 128 + q * 32;
#pragma unroll
    for (int i = 0; i < 8; ++i) qv[i] = *(const float4*)(qp + (((lane + i) & 7) << 2));
  }
  // rope values for this lane's keys (key = s_begin + tile*4 + q)
  float rope_r[NTIL];
  {
    const float* rp = rope + (((size_t)b * 64) + h * 4 + t) * 4096 + s_begin + q;
#pragma unroll
    for (int i = 0; i < NTIL; ++i) rope_r[i] = rp[i * 4];
  }

  // staging: wave wv stages row wv of the tile (8 x 1KB contiguous gloads)
  auto issue_tile = [&](int buf, int srow0) {
    const int s = srow0 + wv;
    const float* rowp = (s < 4092)
        ? (ckv_past + ((size_t)b * 4092 + s) * 2048)
        : (out_ckv + ((size_t)(b * 4096 + s)) * 2048);
#pragma unroll
    for (int g = 0; g < 8; ++g) {
      __builtin_amdgcn_global_load_lds(
          (const __attribute__((address_space(1))) void*)(rowp + g * 256 + (lane << 2)),
          (__attribute__((address_space(3))) void*)&kv[buf][wv][g * 256],
          16, 0, 0);
    }
  };

  issue_tile(0, s_begin);
  asm volatile("s_waitcnt lgkmcnt(0)" ::: "memory");

  float m_run = -INFINITY, l_run = 0.f;
  float4 av[8];
#pragma unroll
  for (int i = 0; i < 8; ++i) av[i] = make_float4(0.f, 0.f, 0.f, 0.f);

  int cur = 0;
#pragma unroll
  for (int tile = 0; tile < NTIL; ++tile) {
    const int s0 = s_begin + tile * TROWS;
    if (tile + 1 < NTIL) issue_tile(cur ^ 1, s0 + TROWS);
    if (tile == 0 || tile + 1 == NTIL)
      asm volatile("s_waitcnt vmcnt(8)" ::: "memory");
    else
      asm volatile("s_waitcnt vmcnt(16)" ::: "memory");
    __builtin_amdgcn_s_barrier();      // all 4 rows staged

    __builtin_amdgcn_s_setprio(1);
    // scores for the tile's 4 keys; lane keeps key k == q
    float mydot = 0.f;
#pragma unroll
    for (int k = 0; k < 4; ++k) {
      float d0 = 0.f, d1 = 0.f;
#pragma unroll
      for (int i = 0; i < 8; i += 2) {
        const float4 v0 = *(const float4*)&kv[cur][k][h * 128 + q * 32 + (((lane + i) & 7) << 2)];
        const float4 v1 = *(const float4*)&kv[cur][k][h * 128 + q * 32 + (((lane + i + 1) & 7) << 2)];
        d0 += dot4(qv[i], v0);
        d1 += dot4(qv[i + 1], v1);
      }
      float dk = d0 + d1;
      dk += __shfl_xor(dk, 1, 64);
      dk += __shfl_xor(dk, 2, 64);
      mydot = (k == q) ? dk : mydot;
    }
    const int skey = s0 + q;
    const float sc = (skey <= lim)
        ? (mydot + rope_r[tile]) * 0.07216878364870323f   // 1/sqrt(192)
        : -INFINITY;

    // online softmax per 4-lane (h,t) group (state replicated in all 4 lanes)
    float mt = fmaxf(sc, __shfl_xor(sc, 1, 64));
    mt = fmaxf(mt, __shfl_xor(mt, 2, 64));
    const float m_new = fmaxf(m_run, mt);
    const float p = expf(sc - m_new);     // masked: expf(-inf)=0
    float lt = p + __shfl_xor(p, 1, 64);
    lt = lt + __shfl_xor(lt, 2, 64);
    const float f = expf(m_run - m_new);
    l_run = l_run * f + lt;
#pragma unroll
    for (int i = 0; i < 8; ++i) {
      av[i].x *= f; av[i].y *= f; av[i].z *= f; av[i].w *= f;
    }
    m_run = m_new;

    // p of the group's 4 keys via butterfly (lane-local key order q^j)
    const float p1 = __shfl_xor(p, 1, 64);    // key q^1
    const float p2 = __shfl_xor(p, 2, 64);    // key q^2
    const float p3 = __shfl_xor(p1, 2, 64);   // key q^3

#pragma unroll
    for (int i = 0; i < 8; ++i) {
      const int co = h * 128 + q * 32 + (((lane + i) & 7) << 2);
      const float4 v0 = *(const float4*)&kv[cur][q][co];
      const float4 v1 = *(const float4*)&kv[cur][q ^ 1][co];
      const float4 v2 = *(const float4*)&kv[cur][q ^ 2][co];
      const float4 v3 = *(const float4*)&kv[cur][q ^ 3][co];
      av[i].x += p * v0.x + p1 * v1.x + p2 * v2.x + p3 * v3.x;
      av[i].y += p * v0.y + p1 * v1.y + p2 * v2.y + p3 * v3.y;
      av[i].z += p * v0.z + p1 * v1.z + p2 * v2.z + p3 * v3.z;
      av[i].w += p * v0.w + p1 * v1.w + p2 * v2.w + p3 * v3.w;
    }
    __builtin_amdgcn_s_setprio(0);

    // fused copy-out: wave wv stores row wv (contiguous 1KB stores)
    {
      const int s = s0 + wv;
      if (s < 4092) {
        float* rowo = out_ckv + ((size_t)(b * 4096 + s)) * 2048;
#pragma unroll
        for (int g = 0; g < 8; ++g) {
          const float4 v = *(const float4*)&kv[cur][wv][g * 256 + (lane << 2)];
          *(float4*)(rowo + g * 256 + (lane << 2)) = v;
        }
      }
    }

    __builtin_amdgcn_s_barrier();      // all waves done reading kv[cur]
    cur ^= 1;
  }

  // write partials: acc dims q*32 + ((lane+i)&7)*4
  const size_t base = (((size_t)(b * 16 + h) * 4 + t) * NSPLIT + sp);
#pragma unroll
  for (int i = 0; i < 8; ++i) {
    *(float4*)(part_acc + base * 128 + q * 32 + (((lane + i) & 7) << 2)) = av[i];
  }
  if (q == 0) {
    part_ml[base * 2]     = m_run;
    part_ml[base * 2 + 1] = l_run;
  }
}

// ---------------- combine split partials (two-pass over 64 spans) ------------
__global__ __launch_bounds__(128) void combine_kernel(
    const float* __restrict__ part_acc, const float* __restrict__ part_ml,
    float* __restrict__ merged) {
  const int h = blockIdx.x & 15;
  const int b = blockIdx.x >> 4;
  const int d = threadIdx.x;  // 0..127
#pragma unroll 1
  for (int t = 0; t < 4; ++t) {
    const size_t base0 = ((size_t)(b * 16 + h) * 4 + t) * NSPLIT;
    float m = -INFINITY;
#pragma unroll 1
    for (int sp = 0; sp < NSPLIT; ++sp) m = fmaxf(m, part_ml[(base0 + sp) * 2]);
    float den = 0.f, num = 0.f;
#pragma unroll 1
    for (int sp = 0; sp < NSPLIT; ++sp) {
      const float w = expf(part_ml[(base0 + sp) * 2] - m);
      den += w * part_ml[(base0 + sp) * 2 + 1];
      num += w * part_acc[(base0 + sp) * 128 + d];
    }
    merged[((size_t)(b * 4 + t)) * 2048 + h * 128 + d] = num / den;
  }
}

// ---------------- output projection (K=2048) ---------------------------------
__global__ __launch_bounds__(256) void outproj_kernel(
    const float* __restrict__ A, const float* __restrict__ W_o,
    float* __restrict__ out0) {
  const int wave = threadIdx.x >> 6;
  const int lane = threadIdx.x & 63;
  const int jbase = (blockIdx.x * 4 + wave) * 2;  // 2048 cols
  const float* w0 = W_o + (size_t)jbase * 2048;
  const float* w1 = w0 + 2048;

  __shared__ float wlds[4][2][2048];  // 64 KB

#pragma unroll
  for (int m = 0; m < 8; ++m) {
    __builtin_amdgcn_global_load_lds(
        (const __attribute__((address_space(1))) void*)(w0 + (m << 8) + (lane << 2)),
        (__attribute__((address_space(3))) void*)&wlds[wave][0][m << 8], 16, 0, 0);
    __builtin_amdgcn_global_load_lds(
        (const __attribute__((address_space(1))) void*)(w1 + (m << 8) + (lane << 2)),
        (__attribute__((address_space(3))) void*)&wlds[wave][1][m << 8], 16, 0, 0);
  }
  __syncthreads();

  float acc0[32], acc1[32];
#pragma unroll
  for (int i = 0; i < 32; ++i) { acc0[i] = 0.f; acc1[i] = 0.f; }

#pragma unroll 1
  for (int m = 0; m < 8; ++m) {
    const int k = (lane << 2) + (m << 8);
    const float4 wa = *(const float4*)&wlds[wave][0][k];
    const float4 wb = *(const float4*)&wlds[wave][1][k];
#pragma unroll
    for (int i = 0; i < 32; ++i) {
      const float4 a = *(const float4*)(A + i * 2048 + k);
      acc0[i] += dot4(a, wa);
      acc1[i] += dot4(a, wb);
    }
  }
#pragma unroll
  for (int i = 0; i < 32; ++i) { acc0[i] = wsum(acc0[i]); acc1[i] = wsum(acc1[i]); }
  float myval = 0.f;
#pragma unroll
  for (int i = 0; i < 32; ++i) {
    myval = (lane == i)      ? acc0[i] : myval;
    myval = (lane == i + 32) ? acc1[i] : myval;
  }
  const int mi = lane & 31;
  const int col = jbase + (lane >> 5);
  out0[(size_t)mi * 2048 + col] = myval;
}

extern "C" void kernel_launch(void* const* d_in, const int* in_sizes, int n_in,
                              void* d_out, int out_size, void* d_ws, size_t ws_size,
                              hipStream_t stream) {
  const float* hidden   = (const float*)d_in[0];
  const float* ckv_past = (const float*)d_in[1];
  const float* kr_past  = (const float*)d_in[2];
  // d_in[3] attention_mask: replicated analytically (causal, offset PAST)
  const float* W_dq  = (const float*)d_in[4];
  const float* W_uq  = (const float*)d_in[5];
  const float* W_qr  = (const float*)d_in[6];
  const float* W_dkv = (const float*)d_in[7];
  const float* W_kr  = (const float*)d_in[8];
  const float* W_o   = (const float*)d_in[9];

  float* out0    = (float*)d_out;                       // (8,4,2048)
  float* out_ckv = out0 + (size_t)32 * 2048;            // (8,4096,2048)
  float* out_kr  = out_ckv + (size_t)8 * 4096 * 2048;   // (8,4096,64)

  float* ws       = (float*)d_ws;
  float* ws_cq    = ws;                                  // 32*512
  float* ws_qc    = ws_cq + 32 * 512;                    // 32*2048
  float* ws_qr    = ws_qc + 32 * 2048;                   // 32*1024
  float* part_acc = ws_qr + 32 * 1024;                   // 8*16*4*64*128
  float* part_ml  = part_acc + (size_t)8 * 16 * 4 * NSPLIT * 128;
  float* merged   = part_ml + (size_t)8 * 16 * 4 * NSPLIT * 2;   // 32*2048
  float* rope     = merged + 32 * 2048;                  // 8*64*4096 floats

  hipLaunchKernelGGL(proj1_kernel, dim3(328), dim3(256), 0, stream,
                     hidden, W_dq, W_dkv, W_kr, ws_cq, out_ckv, out_kr);
  hipLaunchKernelGGL(proj2_kernel, dim3(384), dim3(256), 0, stream,
                     ws_cq, W_uq, W_qr, ws_qc, ws_qr);
  hipLaunchKernelGGL(rope_kernel, dim3(64, 8), dim3(256), 0, stream,
                     kr_past, out_kr, ws_qr, rope);
  hipLaunchKernelGGL(attn_kernel, dim3(NSPLIT, 8), dim3(256), 0, stream,
                     ckv_past, out_ckv, ws_qc, rope, part_acc, part_ml);
  hipLaunchKernelGGL(combine_kernel, dim3(128), dim3(128), 0, stream,
                     part_acc, part_ml, merged);
  hipLaunchKernelGGL(outproj_kernel, dim3(256), dim3(256), 0, stream,
                     merged, W_o, out0);
}

// Round 19
// 190.918 us; speedup vs baseline: 5.1107x; 5.1107x over previous
//
#include <hip/hip_runtime.h>
#include <math.h>

#define NSPLIT 4
#define KB 64
#define SPLIT_KEYS 1024
#define NTILES (SPLIT_KEYS / KB)

typedef float vfloat4 __attribute__((ext_vector_type(4)));

__device__ __forceinline__ float wsum(float v) {
#pragma unroll
  for (int off = 32; off >= 1; off >>= 1) v += __shfl_xor(v, off, 64);
  return v;
}
__device__ __forceinline__ float wmax(float v) {
#pragma unroll
  for (int off = 32; off >= 1; off >>= 1) v = fmaxf(v, __shfl_xor(v, off, 64));
  return v;
}
__device__ __forceinline__ float dot4(const float4 a, const float4 b) {
  return a.x * b.x + a.y * b.y + a.z * b.z + a.w * b.w;
}

// ---------------- proj1: c_q / c_kv_new / k_rope_new from hidden (K=2048) ----
// Wave's full weight slice staged via global_load_lds (full HBM BW, no VGPR).
__global__ __launch_bounds__(256) void proj1_kernel(
    const float* __restrict__ hidden, const float* __restrict__ W_dq,
    const float* __restrict__ W_dkv, const float* __restrict__ W_kr,
    float* __restrict__ ws_cq, float* __restrict__ out_ckv,
    float* __restrict__ out_kr) {
  const int wave = threadIdx.x >> 6;
  const int lane = threadIdx.x & 63;
  const int jbase = (blockIdx.x * 4 + wave) * 2;  // 2624 cols total
  const float* w0;
  if (jbase < 512)       w0 = W_dq  + (size_t)jbase * 2048;
  else if (jbase < 2560) w0 = W_dkv + (size_t)(jbase - 512) * 2048;
  else                   w0 = W_kr  + (size_t)(jbase - 2560) * 2048;
  const float* w1 = w0 + 2048;

  __shared__ float wlds[4][2][2048];  // 64 KB

#pragma unroll
  for (int m = 0; m < 8; ++m) {
    __builtin_amdgcn_global_load_lds(
        (const __attribute__((address_space(1))) void*)(w0 + (m << 8) + (lane << 2)),
        (__attribute__((address_space(3))) void*)&wlds[wave][0][m << 8], 16, 0, 0);
    __builtin_amdgcn_global_load_lds(
        (const __attribute__((address_space(1))) void*)(w1 + (m << 8) + (lane << 2)),
        (__attribute__((address_space(3))) void*)&wlds[wave][1][m << 8], 16, 0, 0);
  }
  __syncthreads();   // drains vmcnt; weights in LDS

  float acc0[32], acc1[32];
#pragma unroll
  for (int i = 0; i < 32; ++i) { acc0[i] = 0.f; acc1[i] = 0.f; }

#pragma unroll 1
  for (int m = 0; m < 8; ++m) {
    const int k = (lane << 2) + (m << 8);
    const float4 wa = *(const float4*)&wlds[wave][0][k];
    const float4 wb = *(const float4*)&wlds[wave][1][k];
#pragma unroll
    for (int i = 0; i < 32; ++i) {
      const float4 a = *(const float4*)(hidden + i * 2048 + k);
      acc0[i] += dot4(a, wa);
      acc1[i] += dot4(a, wb);
    }
  }
#pragma unroll
  for (int i = 0; i < 32; ++i) { acc0[i] = wsum(acc0[i]); acc1[i] = wsum(acc1[i]); }

  if (jbase >= 2560) {  // RoPE on k_rope_new, position = t
    const int r0 = jbase - 2560;  // even
    const float inv = powf(10000.f, -(float)r0 / 64.f);
    float cs[4], sn[4];
#pragma unroll
    for (int t = 0; t < 4; ++t) { cs[t] = cosf((float)t * inv); sn[t] = sinf((float)t * inv); }
#pragma unroll
    for (int i = 0; i < 32; ++i) {
      const int t = i & 3;
      const float x0 = acc0[i], x1 = acc1[i];
      acc0[i] = x0 * cs[t] - x1 * sn[t];
      acc1[i] = x0 * sn[t] + x1 * cs[t];
    }
  }

  float myval = 0.f;
#pragma unroll
  for (int i = 0; i < 32; ++i) {
    myval = (lane == i)      ? acc0[i] : myval;
    myval = (lane == i + 32) ? acc1[i] : myval;
  }
  const int mi = lane & 31;               // row (b*4+t)
  const int col = jbase + (lane >> 5);
  const int b = mi >> 2, t = mi & 3;
  if (col < 512)
    ws_cq[mi * 512 + col] = myval;
  else if (col < 2560)
    out_ckv[((size_t)(b * 4096 + 4092 + t)) * 2048 + (col - 512)] = myval;
  else
    out_kr[((size_t)(b * 4096 + 4092 + t)) * 64 + (col - 2560)] = myval;
}

// ---------------- proj2: q_c / q_r (+RoPE) from c_q (K=512) ------------------
__global__ __launch_bounds__(256) void proj2_kernel(
    const float* __restrict__ cq, const float* __restrict__ W_uq,
    const float* __restrict__ W_qr, float* __restrict__ ws_qc,
    float* __restrict__ ws_qr) {
  const int wave = threadIdx.x >> 6;
  const int lane = threadIdx.x & 63;
  const int jbase = (blockIdx.x * 4 + wave) * 2;  // 3072 cols total
  const float* w0 = (jbase < 2048) ? (W_uq + (size_t)jbase * 512)
                                   : (W_qr + (size_t)(jbase - 2048) * 512);
  const float* w1 = w0 + 512;

  __shared__ float wlds[4][2][512];  // 16 KB

#pragma unroll
  for (int m = 0; m < 2; ++m) {
    __builtin_amdgcn_global_load_lds(
        (const __attribute__((address_space(1))) void*)(w0 + (m << 8) + (lane << 2)),
        (__attribute__((address_space(3))) void*)&wlds[wave][0][m << 8], 16, 0, 0);
    __builtin_amdgcn_global_load_lds(
        (const __attribute__((address_space(1))) void*)(w1 + (m << 8) + (lane << 2)),
        (__attribute__((address_space(3))) void*)&wlds[wave][1][m << 8], 16, 0, 0);
  }
  __syncthreads();

  float acc0[32], acc1[32];
#pragma unroll
  for (int i = 0; i < 32; ++i) { acc0[i] = 0.f; acc1[i] = 0.f; }

#pragma unroll 1
  for (int m = 0; m < 2; ++m) {
    const int k = (lane << 2) + (m << 8);
    const float4 wa = *(const float4*)&wlds[wave][0][k];
    const float4 wb = *(const float4*)&wlds[wave][1][k];
#pragma unroll
    for (int i = 0; i < 32; ++i) {
      const float4 a = *(const float4*)(cq + i * 512 + k);
      acc0[i] += dot4(a, wa);
      acc1[i] += dot4(a, wb);
    }
  }
#pragma unroll
  for (int i = 0; i < 32; ++i) { acc0[i] = wsum(acc0[i]); acc1[i] = wsum(acc1[i]); }

  if (jbase >= 2048) {  // RoPE on q_r, position = t
    const int r0 = (jbase - 2048) & 63;  // even
    const float inv = powf(10000.f, -(float)r0 / 64.f);
    float cs[4], sn[4];
#pragma unroll
    for (int t = 0; t < 4; ++t) { cs[t] = cosf((float)t * inv); sn[t] = sinf((float)t * inv); }
#pragma unroll
    for (int i = 0; i < 32; ++i) {
      const int t = i & 3;
      const float x0 = acc0[i], x1 = acc1[i];
      acc0[i] = x0 * cs[t] - x1 * sn[t];
      acc1[i] = x0 * sn[t] + x1 * cs[t];
    }
  }

  float myval = 0.f;
#pragma unroll
  for (int i = 0; i < 32; ++i) {
    myval = (lane == i)      ? acc0[i] : myval;
    myval = (lane == i + 32) ? acc1[i] : myval;
  }
  const int mi = lane & 31;
  const int col = jbase + (lane >> 5);
  if (col < 2048) ws_qc[mi * 2048 + col] = myval;
  else            ws_qr[mi * 1024 + (col - 2048)] = myval;
}

// ---------------- rope scores: rope[b][h*4+t][s] = q_r . k_rope  -------------
__global__ __launch_bounds__(256) void rope_kernel(
    const float* __restrict__ kr_past, float* __restrict__ out_kr,
    const float* __restrict__ qr_g, float* __restrict__ rope) {
  const int chunk = blockIdx.x;  // 64 keys per chunk
  const int b = blockIdx.y;
  const int tid = threadIdx.x;
  const int wave = tid >> 6;
  const int lane = tid & 63;
  const int s0 = chunk * 64;

  __shared__ float krt[64][68];
  __shared__ float sc[64][65];

#pragma unroll
  for (int u = 0; u < 4; ++u) {
    const int fi = tid + u * 256;
    const int row = fi >> 4;
    const int c4  = (fi & 15) << 2;
    const int s = s0 + row;
    float4 v;
    if (s < 4092) {
      v = *(const float4*)(kr_past + ((size_t)b * 4092 + s) * 64 + c4);
      *(float4*)(out_kr + ((size_t)(b * 4096 + s)) * 64 + c4) = v;
    } else {
      v = *(const float4*)(out_kr + ((size_t)(b * 4096 + s)) * 64 + c4);
    }
    *(float4*)&krt[row][c4] = v;
  }

  float4 q[16];
  {
    const float* qrp = qr_g + ((size_t)(b * 4 + (lane & 3))) * 1024 + (lane >> 2) * 64;
#pragma unroll
    for (int m = 0; m < 16; ++m) q[m] = *(const float4*)(qrp + (m << 2));
  }
  __syncthreads();

#pragma unroll 1
  for (int j = 0; j < 16; ++j) {
    const int sl = wave * 16 + j;
    float sum = 0.f;
#pragma unroll
    for (int r = 0; r < 16; ++r) {
      const float4 kv4 = *(const float4*)&krt[sl][r << 2];
      sum += dot4(q[r], kv4);
    }
    sc[lane][sl] = sum;
  }
  __syncthreads();

#pragma unroll
  for (int u = 0; u < 16; ++u) {
    const int e = tid + u * 256;
    const int ht = e >> 6, sl = e & 63;
    rope[((size_t)b * 64 + ht) * 4096 + s0 + sl] = sc[ht][sl];
  }
}

// ---------------- flash attention + fused c_kv copy --------------------------
// r14 structure (best 200.7 us) + ONE change: copy-out uses non-temporal
// stores (ext_vector_type alias; HIP float4 rejected by the builtin). The
// 270MB write stream is never re-read; nt removes L2 write-allocate pressure.
__global__ __launch_bounds__(256) void attn_kernel(
    const float* __restrict__ ckv_past, float* __restrict__ out_ckv,
    const float* __restrict__ qc_g, const float* __restrict__ rope,
    float* __restrict__ part_acc, float* __restrict__ part_ml) {
  const int sp = blockIdx.x;
  const int h  = blockIdx.y;
  const int b  = blockIdx.z;
  const int tid  = threadIdx.x;
  const int wv   = tid >> 6;
  const int lane = tid & 63;
  const int t = wv;  // wave owns query position t

  __shared__ float kv[2][64][128];  // 64 KB (2 buffers)
  __shared__ float qc[4][128];      //  2 KB -> 2 blocks/CU

  // stage q for this (b,h)
#pragma unroll
  for (int rep = 0; rep < 2; ++rep) {
    const int idx = tid + rep * 256;
    const int tt = idx >> 7, d = idx & 127;
    qc[tt][d] = qc_g[((size_t)(b * 4 + tt)) * 2048 + h * 128 + d];
  }

  const float* rope_pt = rope + ((size_t)b * 64 + h * 4 + t) * 4096;
  const int lim = 4092 + t;       // inclusive causal limit
  const int s_begin = sp * SPLIT_KEYS;

  const int lrow = lane >> 5;     // 0..1
  const int pos  = lane & 31;     // 16B slot within row

  auto issue_tile = [&](int buf, int sbase) {
#pragma unroll
    for (int u = 0; u < 8; ++u) {
      const int row = 8 * u + 2 * wv + lrow;
      const int c = pos ^ (row & 7);           // source chunk for this LDS slot
      const int s = sbase + row;
      const float* src = (s < 4092)
          ? (ckv_past + ((size_t)b * 4092 + s) * 2048 + h * 128 + (c << 2))
          : (out_ckv + ((size_t)(b * 4096 + s)) * 2048 + h * 128 + (c << 2));
      __builtin_amdgcn_global_load_lds(
          (const __attribute__((address_space(1))) void*)src,
          (__attribute__((address_space(3))) void*)&kv[buf][8 * u + 2 * wv][0],
          16, 0, 0);
    }
  };

  issue_tile(0, s_begin);                         // prefetch tile 0
  asm volatile("s_waitcnt lgkmcnt(0)" ::: "memory");

  float m_run = -INFINITY, l_run = 0.f;
  float accX0 = 0.f, accX1 = 0.f;   // even kk partial
  float accY0 = 0.f, accY1 = 0.f;   // odd kk partial
  float rope_cur = rope_pt[s_begin + lane];
  int cur = 0;

#pragma unroll 1
  for (int tile = 0; tile < NTILES; ++tile) {
    const int s0 = s_begin + tile * KB;
    if (tile + 1 < NTILES) issue_tile(cur ^ 1, s0 + KB);
    if (tile == 0 || tile + 1 == NTILES)
      asm volatile("s_waitcnt vmcnt(8)" ::: "memory");
    else
      asm volatile("s_waitcnt vmcnt(16)" ::: "memory");
    __builtin_amdgcn_s_barrier();                 // all waves' rows in LDS

    __builtin_amdgcn_s_setprio(1);
    // prefetch next tile's rope value (hides the ~200cy L2 hit under compute)
    float rope_next = 0.f;
    if (tile + 1 < NTILES) rope_next = rope_pt[s0 + KB + lane];

    // scores: lane = key within tile, wave = query t; 2 partial sums (ILP)
    const int s = s0 + lane;
    float sc = -INFINITY;
    if (s <= lim) {
      float sumA = rope_cur, sumB = 0.f;
#pragma unroll
      for (int cc = 0; cc < 32; cc += 2) {
        const float4 kv0 = *(const float4*)&kv[cur][lane][(cc ^ (lane & 7)) << 2];
        const float4 kv1 = *(const float4*)&kv[cur][lane][((cc + 1) ^ (lane & 7)) << 2];
        sumA += dot4(kv0, *(const float4*)&qc[t][cc << 2]);
        sumB += dot4(kv1, *(const float4*)&qc[t][(cc + 1) << 2]);
      }
      sc = (sumA + sumB) * 0.07216878364870323f;  // 1/sqrt(192)
    }
    const float mt = wmax(sc);
    const float m_new = fmaxf(m_run, mt);
    const float p = expf(sc - m_new);   // masked: expf(-inf)=0
    const float lt = wsum(p);
    const float f = expf(m_run - m_new);
    l_run = l_run * f + lt;
    accX0 *= f; accX1 *= f; accY0 *= f; accY1 *= f;
    m_run = m_new;

    // PV: lane owns dims (2*lane, 2*lane+1); kk in pairs, 2 indep acc chains
    const int c0 = lane >> 1;
    const int off = (lane & 1) << 1;
    const int pu = __float_as_int(p);
#pragma unroll
    for (int kk = 0; kk < KB; kk += 2) {
      const float pv0 = __int_as_float(__builtin_amdgcn_readlane(pu, kk));
      const float pv1 = __int_as_float(__builtin_amdgcn_readlane(pu, kk + 1));
      const float2 vv0 = *(const float2*)&kv[cur][kk][((c0 ^ (kk & 7)) << 2) + off];
      const float2 vv1 = *(const float2*)&kv[cur][kk + 1][((c0 ^ ((kk + 1) & 7)) << 2) + off];
      accX0 += pv0 * vv0.x;
      accX1 += pv0 * vv0.y;
      accY0 += pv1 * vv1.x;
      accY1 += pv1 * vv1.y;
    }
    __builtin_amdgcn_s_setprio(0);

    // fused copy-out of past rows: LDS -> out_ckv, NON-TEMPORAL stores
    // (write stream is never re-read; keep it out of L2)
#pragma unroll
    for (int u = 0; u < 8; ++u) {
      const int fi = tid + u * 256;
      const int row = fi >> 5;
      const int c   = fi & 31;
      const int ss = s0 + row;
      if (ss < 4092) {
        const vfloat4 v = *(const vfloat4*)&kv[cur][row][(c ^ (row & 7)) << 2];
        __builtin_nontemporal_store(
            v, (vfloat4*)(out_ckv + ((size_t)(b * 4096 + ss)) * 2048 + h * 128 + (c << 2)));
      }
    }

    __builtin_amdgcn_s_barrier();   // all waves done reading kv[cur]
    cur ^= 1;
    rope_cur = rope_next;
  }

  const size_t base = ((size_t)((b * 16 + h) * 4 + t)) * NSPLIT + sp;
  part_acc[base * 128 + (lane << 1)]     = accX0 + accY0;
  part_acc[base * 128 + (lane << 1) + 1] = accX1 + accY1;
  if (lane == 0) {
    part_ml[base * 2]     = m_run;
    part_ml[base * 2 + 1] = l_run;
  }
}

// ---------------- combine split partials -------------------------------------
__global__ __launch_bounds__(128) void combine_kernel(
    const float* __restrict__ part_acc, const float* __restrict__ part_ml,
    float* __restrict__ merged) {
  const int h = blockIdx.x & 15;
  const int b = blockIdx.x >> 4;
  const int d = threadIdx.x;  // 0..127
#pragma unroll
  for (int t = 0; t < 4; ++t) {
    const size_t base = ((size_t)((b * 16 + h) * 4 + t)) * NSPLIT;
    float mm[NSPLIT], ll[NSPLIT];
    float m = -INFINITY;
#pragma unroll
    for (int sp = 0; sp < NSPLIT; ++sp) {
      mm[sp] = part_ml[(base + sp) * 2];
      ll[sp] = part_ml[(base + sp) * 2 + 1];
      m = fmaxf(m, mm[sp]);
    }
    float den = 0.f, num = 0.f;
#pragma unroll
    for (int sp = 0; sp < NSPLIT; ++sp) {
      const float w = expf(mm[sp] - m);
      den += w * ll[sp];
      num += w * part_acc[(base + sp) * 128 + d];
    }
    merged[((size_t)(b * 4 + t)) * 2048 + h * 128 + d] = num / den;
  }
}

// ---------------- output projection (K=2048) ---------------------------------
__global__ __launch_bounds__(256) void outproj_kernel(
    const float* __restrict__ A, const float* __restrict__ W_o,
    float* __restrict__ out0) {
  const int wave = threadIdx.x >> 6;
  const int lane = threadIdx.x & 63;
  const int jbase = (blockIdx.x * 4 + wave) * 2;  // 2048 cols
  const float* w0 = W_o + (size_t)jbase * 2048;
  const float* w1 = w0 + 2048;

  __shared__ float wlds[4][2][2048];  // 64 KB

#pragma unroll
  for (int m = 0; m < 8; ++m) {
    __builtin_amdgcn_global_load_lds(
        (const __attribute__((address_space(1))) void*)(w0 + (m << 8) + (lane << 2)),
        (__attribute__((address_space(3))) void*)&wlds[wave][0][m << 8], 16, 0, 0);
    __builtin_amdgcn_global_load_lds(
        (const __attribute__((address_space(1))) void*)(w1 + (m << 8) + (lane << 2)),
        (__attribute__((address_space(3))) void*)&wlds[wave][1][m << 8], 16, 0, 0);
  }
  __syncthreads();

  float acc0[32], acc1[32];
#pragma unroll
  for (int i = 0; i < 32; ++i) { acc0[i] = 0.f; acc1[i] = 0.f; }

#pragma unroll 1
  for (int m = 0; m < 8; ++m) {
    const int k = (lane << 2) + (m << 8);
    const float4 wa = *(const float4*)&wlds[wave][0][k];
    const float4 wb = *(const float4*)&wlds[wave][1][k];
#pragma unroll
    for (int i = 0; i < 32; ++i) {
      const float4 a = *(const float4*)(A + i * 2048 + k);
      acc0[i] += dot4(a, wa);
      acc1[i] += dot4(a, wb);
    }
  }
#pragma unroll
  for (int i = 0; i < 32; ++i) { acc0[i] = wsum(acc0[i]); acc1[i] = wsum(acc1[i]); }
  float myval = 0.f;
#pragma unroll
  for (int i = 0; i < 32; ++i) {
    myval = (lane == i)      ? acc0[i] : myval;
    myval = (lane == i + 32) ? acc1[i] : myval;
  }
  const int mi = lane & 31;
  const int col = jbase + (lane >> 5);
  out0[(size_t)mi * 2048 + col] = myval;
}

extern "C" void kernel_launch(void* const* d_in, const int* in_sizes, int n_in,
                              void* d_out, int out_size, void* d_ws, size_t ws_size,
                              hipStream_t stream) {
  const float* hidden   = (const float*)d_in[0];
  const float* ckv_past = (const float*)d_in[1];
  const float* kr_past  = (const float*)d_in[2];
  // d_in[3] attention_mask: replicated analytically (causal, offset PAST)
  const float* W_dq  = (const float*)d_in[4];
  const float* W_uq  = (const float*)d_in[5];
  const float* W_qr  = (const float*)d_in[6];
  const float* W_dkv = (const float*)d_in[7];
  const float* W_kr  = (const float*)d_in[8];
  const float* W_o   = (const float*)d_in[9];

  float* out0    = (float*)d_out;                       // (8,4,2048)
  float* out_ckv = out0 + (size_t)32 * 2048;            // (8,4096,2048)
  float* out_kr  = out_ckv + (size_t)8 * 4096 * 2048;   // (8,4096,64)

  float* ws       = (float*)d_ws;
  float* ws_cq    = ws;                                  // 32*512
  float* ws_qc    = ws_cq + 32 * 512;                    // 32*2048
  float* ws_qr    = ws_qc + 32 * 2048;                   // 32*1024
  float* part_acc = ws_qr + 32 * 1024;                   // 8*16*4*NSPLIT*128
  float* part_ml  = part_acc + (size_t)8 * 16 * 4 * NSPLIT * 128;
  float* merged   = part_ml + (size_t)8 * 16 * 4 * NSPLIT * 2;   // 32*2048
  float* rope     = merged + 32 * 2048;                  // 8*64*4096 floats

  hipLaunchKernelGGL(proj1_kernel, dim3(328), dim3(256), 0, stream,
                     hidden, W_dq, W_dkv, W_kr, ws_cq, out_ckv, out_kr);
  hipLaunchKernelGGL(proj2_kernel, dim3(384), dim3(256), 0, stream,
                     ws_cq, W_uq, W_qr, ws_qc, ws_qr);
  hipLaunchKernelGGL(rope_kernel, dim3(64, 8), dim3(256), 0, stream,
                     kr_past, out_kr, ws_qr, rope);
  hipLaunchKernelGGL(attn_kernel, dim3(NSPLIT, 16, 8), dim3(256), 0, stream,
                     ckv_past, out_ckv, ws_qc, rope, part_acc, part_ml);
  hipLaunchKernelGGL(combine_kernel, dim3(128), dim3(128), 0, stream,
                     part_acc, part_ml, merged);
  hipLaunchKernelGGL(outproj_kernel, dim3(256), dim3(256), 0, stream,
                     merged, W_o, out0);
}

// Round 20
// 189.227 us; speedup vs baseline: 5.1564x; 1.0089x over previous
//
#include <hip/hip_runtime.h>
#include <math.h>

#define NSPLIT 4
#define KB 64
#define SPLIT_KEYS 1024
#define NTILES (SPLIT_KEYS / KB)
#define AUX_NT 2   // gfx94x/gfx950 CPol: bit1 = NT (streaming, no L2 allocate)

typedef float vfloat4 __attribute__((ext_vector_type(4)));

__device__ __forceinline__ float wsum(float v) {
#pragma unroll
  for (int off = 32; off >= 1; off >>= 1) v += __shfl_xor(v, off, 64);
  return v;
}
__device__ __forceinline__ float wmax(float v) {
#pragma unroll
  for (int off = 32; off >= 1; off >>= 1) v = fmaxf(v, __shfl_xor(v, off, 64));
  return v;
}
__device__ __forceinline__ float dot4(const float4 a, const float4 b) {
  return a.x * b.x + a.y * b.y + a.z * b.z + a.w * b.w;
}

// ---------------- proj1: c_q / c_kv_new / k_rope_new from hidden (K=2048) ----
__global__ __launch_bounds__(256) void proj1_kernel(
    const float* __restrict__ hidden, const float* __restrict__ W_dq,
    const float* __restrict__ W_dkv, const float* __restrict__ W_kr,
    float* __restrict__ ws_cq, float* __restrict__ out_ckv,
    float* __restrict__ out_kr) {
  const int wave = threadIdx.x >> 6;
  const int lane = threadIdx.x & 63;
  const int jbase = (blockIdx.x * 4 + wave) * 2;  // 2624 cols total
  const float* w0;
  if (jbase < 512)       w0 = W_dq  + (size_t)jbase * 2048;
  else if (jbase < 2560) w0 = W_dkv + (size_t)(jbase - 512) * 2048;
  else                   w0 = W_kr  + (size_t)(jbase - 2560) * 2048;
  const float* w1 = w0 + 2048;

  __shared__ float wlds[4][2][2048];  // 64 KB

#pragma unroll
  for (int m = 0; m < 8; ++m) {
    __builtin_amdgcn_global_load_lds(
        (const __attribute__((address_space(1))) void*)(w0 + (m << 8) + (lane << 2)),
        (__attribute__((address_space(3))) void*)&wlds[wave][0][m << 8], 16, 0, AUX_NT);
    __builtin_amdgcn_global_load_lds(
        (const __attribute__((address_space(1))) void*)(w1 + (m << 8) + (lane << 2)),
        (__attribute__((address_space(3))) void*)&wlds[wave][1][m << 8], 16, 0, AUX_NT);
  }
  __syncthreads();   // drains vmcnt; weights in LDS

  float acc0[32], acc1[32];
#pragma unroll
  for (int i = 0; i < 32; ++i) { acc0[i] = 0.f; acc1[i] = 0.f; }

#pragma unroll 1
  for (int m = 0; m < 8; ++m) {
    const int k = (lane << 2) + (m << 8);
    const float4 wa = *(const float4*)&wlds[wave][0][k];
    const float4 wb = *(const float4*)&wlds[wave][1][k];
#pragma unroll
    for (int i = 0; i < 32; ++i) {
      const float4 a = *(const float4*)(hidden + i * 2048 + k);
      acc0[i] += dot4(a, wa);
      acc1[i] += dot4(a, wb);
    }
  }
#pragma unroll
  for (int i = 0; i < 32; ++i) { acc0[i] = wsum(acc0[i]); acc1[i] = wsum(acc1[i]); }

  if (jbase >= 2560) {  // RoPE on k_rope_new, position = t
    const int r0 = jbase - 2560;  // even
    const float inv = powf(10000.f, -(float)r0 / 64.f);
    float cs[4], sn[4];
#pragma unroll
    for (int t = 0; t < 4; ++t) { cs[t] = cosf((float)t * inv); sn[t] = sinf((float)t * inv); }
#pragma unroll
    for (int i = 0; i < 32; ++i) {
      const int t = i & 3;
      const float x0 = acc0[i], x1 = acc1[i];
      acc0[i] = x0 * cs[t] - x1 * sn[t];
      acc1[i] = x0 * sn[t] + x1 * cs[t];
    }
  }

  float myval = 0.f;
#pragma unroll
  for (int i = 0; i < 32; ++i) {
    myval = (lane == i)      ? acc0[i] : myval;
    myval = (lane == i + 32) ? acc1[i] : myval;
  }
  const int mi = lane & 31;               // row (b*4+t)
  const int col = jbase + (lane >> 5);
  const int b = mi >> 2, t = mi & 3;
  if (col < 512)
    ws_cq[mi * 512 + col] = myval;
  else if (col < 2560)
    out_ckv[((size_t)(b * 4096 + 4092 + t)) * 2048 + (col - 512)] = myval;
  else
    out_kr[((size_t)(b * 4096 + 4092 + t)) * 64 + (col - 2560)] = myval;
}

// ---------------- proj2: q_c / q_r (+RoPE) from c_q (K=512) ------------------
__global__ __launch_bounds__(256) void proj2_kernel(
    const float* __restrict__ cq, const float* __restrict__ W_uq,
    const float* __restrict__ W_qr, float* __restrict__ ws_qc,
    float* __restrict__ ws_qr) {
  const int wave = threadIdx.x >> 6;
  const int lane = threadIdx.x & 63;
  const int jbase = (blockIdx.x * 4 + wave) * 2;  // 3072 cols total
  const float* w0 = (jbase < 2048) ? (W_uq + (size_t)jbase * 512)
                                   : (W_qr + (size_t)(jbase - 2048) * 512);
  const float* w1 = w0 + 512;

  __shared__ float wlds[4][2][512];  // 16 KB

#pragma unroll
  for (int m = 0; m < 2; ++m) {
    __builtin_amdgcn_global_load_lds(
        (const __attribute__((address_space(1))) void*)(w0 + (m << 8) + (lane << 2)),
        (__attribute__((address_space(3))) void*)&wlds[wave][0][m << 8], 16, 0, AUX_NT);
    __builtin_amdgcn_global_load_lds(
        (const __attribute__((address_space(1))) void*)(w1 + (m << 8) + (lane << 2)),
        (__attribute__((address_space(3))) void*)&wlds[wave][1][m << 8], 16, 0, AUX_NT);
  }
  __syncthreads();

  float acc0[32], acc1[32];
#pragma unroll
  for (int i = 0; i < 32; ++i) { acc0[i] = 0.f; acc1[i] = 0.f; }

#pragma unroll 1
  for (int m = 0; m < 2; ++m) {
    const int k = (lane << 2) + (m << 8);
    const float4 wa = *(const float4*)&wlds[wave][0][k];
    const float4 wb = *(const float4*)&wlds[wave][1][k];
#pragma unroll
    for (int i = 0; i < 32; ++i) {
      const float4 a = *(const float4*)(cq + i * 512 + k);
      acc0[i] += dot4(a, wa);
      acc1[i] += dot4(a, wb);
    }
  }
#pragma unroll
  for (int i = 0; i < 32; ++i) { acc0[i] = wsum(acc0[i]); acc1[i] = wsum(acc1[i]); }

  if (jbase >= 2048) {  // RoPE on q_r, position = t
    const int r0 = (jbase - 2048) & 63;  // even
    const float inv = powf(10000.f, -(float)r0 / 64.f);
    float cs[4], sn[4];
#pragma unroll
    for (int t = 0; t < 4; ++t) { cs[t] = cosf((float)t * inv); sn[t] = sinf((float)t * inv); }
#pragma unroll
    for (int i = 0; i < 32; ++i) {
      const int t = i & 3;
      const float x0 = acc0[i], x1 = acc1[i];
      acc0[i] = x0 * cs[t] - x1 * sn[t];
      acc1[i] = x0 * sn[t] + x1 * cs[t];
    }
  }

  float myval = 0.f;
#pragma unroll
  for (int i = 0; i < 32; ++i) {
    myval = (lane == i)      ? acc0[i] : myval;
    myval = (lane == i + 32) ? acc1[i] : myval;
  }
  const int mi = lane & 31;
  const int col = jbase + (lane >> 5);
  if (col < 2048) ws_qc[mi * 2048 + col] = myval;
  else            ws_qr[mi * 1024 + (col - 2048)] = myval;
}

// ---------------- rope scores: rope[b][h*4+t][s] = q_r . k_rope  -------------
__global__ __launch_bounds__(256) void rope_kernel(
    const float* __restrict__ kr_past, float* __restrict__ out_kr,
    const float* __restrict__ qr_g, float* __restrict__ rope) {
  const int chunk = blockIdx.x;  // 64 keys per chunk
  const int b = blockIdx.y;
  const int tid = threadIdx.x;
  const int wave = tid >> 6;
  const int lane = tid & 63;
  const int s0 = chunk * 64;

  __shared__ float krt[64][68];
  __shared__ float sc[64][65];

#pragma unroll
  for (int u = 0; u < 4; ++u) {
    const int fi = tid + u * 256;
    const int row = fi >> 4;
    const int c4  = (fi & 15) << 2;
    const int s = s0 + row;
    float4 v;
    if (s < 4092) {
      v = *(const float4*)(kr_past + ((size_t)b * 4092 + s) * 64 + c4);
      __builtin_nontemporal_store(
          *(const vfloat4*)&v,
          (vfloat4*)(out_kr + ((size_t)(b * 4096 + s)) * 64 + c4));
    } else {
      v = *(const float4*)(out_kr + ((size_t)(b * 4096 + s)) * 64 + c4);
    }
    *(float4*)&krt[row][c4] = v;
  }

  float4 q[16];
  {
    const float* qrp = qr_g + ((size_t)(b * 4 + (lane & 3))) * 1024 + (lane >> 2) * 64;
#pragma unroll
    for (int m = 0; m < 16; ++m) q[m] = *(const float4*)(qrp + (m << 2));
  }
  __syncthreads();

#pragma unroll 1
  for (int j = 0; j < 16; ++j) {
    const int sl = wave * 16 + j;
    float sum = 0.f;
#pragma unroll
    for (int r = 0; r < 16; ++r) {
      const float4 kv4 = *(const float4*)&krt[sl][r << 2];
      sum += dot4(q[r], kv4);
    }
    sc[lane][sl] = sum;
  }
  __syncthreads();

#pragma unroll
  for (int u = 0; u < 16; ++u) {
    const int e = tid + u * 256;
    const int ht = e >> 6, sl = e & 63;
    rope[((size_t)b * 64 + ht) * 4096 + s0 + sl] = sc[ht][sl];
  }
}

// ---------------- flash attention + fused c_kv copy --------------------------
// r19 (best 190.9) + NT on the zero-reuse READ streams: ckv via gload_lds
// aux=NT, rope via nontemporal_load. Copy-out already NT stores.
__global__ __launch_bounds__(256) void attn_kernel(
    const float* __restrict__ ckv_past, float* __restrict__ out_ckv,
    const float* __restrict__ qc_g, const float* __restrict__ rope,
    float* __restrict__ part_acc, float* __restrict__ part_ml) {
  const int sp = blockIdx.x;
  const int h  = blockIdx.y;
  const int b  = blockIdx.z;
  const int tid  = threadIdx.x;
  const int wv   = tid >> 6;
  const int lane = tid & 63;
  const int t = wv;  // wave owns query position t

  __shared__ float kv[2][64][128];  // 64 KB (2 buffers)
  __shared__ float qc[4][128];      //  2 KB -> 2 blocks/CU

  // stage q for this (b,h)
#pragma unroll
  for (int rep = 0; rep < 2; ++rep) {
    const int idx = tid + rep * 256;
    const int tt = idx >> 7, d = idx & 127;
    qc[tt][d] = qc_g[((size_t)(b * 4 + tt)) * 2048 + h * 128 + d];
  }

  const float* rope_pt = rope + ((size_t)b * 64 + h * 4 + t) * 4096;
  const int lim = 4092 + t;       // inclusive causal limit
  const int s_begin = sp * SPLIT_KEYS;

  const int lrow = lane >> 5;     // 0..1
  const int pos  = lane & 31;     // 16B slot within row

  auto issue_tile = [&](int buf, int sbase) {
#pragma unroll
    for (int u = 0; u < 8; ++u) {
      const int row = 8 * u + 2 * wv + lrow;
      const int c = pos ^ (row & 7);           // source chunk for this LDS slot
      const int s = sbase + row;
      const float* src = (s < 4092)
          ? (ckv_past + ((size_t)b * 4092 + s) * 2048 + h * 128 + (c << 2))
          : (out_ckv + ((size_t)(b * 4096 + s)) * 2048 + h * 128 + (c << 2));
      __builtin_amdgcn_global_load_lds(
          (const __attribute__((address_space(1))) void*)src,
          (__attribute__((address_space(3))) void*)&kv[buf][8 * u + 2 * wv][0],
          16, 0, AUX_NT);
    }
  };

  issue_tile(0, s_begin);                         // prefetch tile 0
  asm volatile("s_waitcnt lgkmcnt(0)" ::: "memory");

  float m_run = -INFINITY, l_run = 0.f;
  float accX0 = 0.f, accX1 = 0.f;   // even kk partial
  float accY0 = 0.f, accY1 = 0.f;   // odd kk partial
  float rope_cur = __builtin_nontemporal_load(rope_pt + s_begin + lane);
  int cur = 0;

#pragma unroll 1
  for (int tile = 0; tile < NTILES; ++tile) {
    const int s0 = s_begin + tile * KB;
    if (tile + 1 < NTILES) issue_tile(cur ^ 1, s0 + KB);
    if (tile == 0 || tile + 1 == NTILES)
      asm volatile("s_waitcnt vmcnt(8)" ::: "memory");
    else
      asm volatile("s_waitcnt vmcnt(16)" ::: "memory");
    __builtin_amdgcn_s_barrier();                 // all waves' rows in LDS

    __builtin_amdgcn_s_setprio(1);
    // prefetch next tile's rope value (hides the ~200cy hit under compute)
    float rope_next = 0.f;
    if (tile + 1 < NTILES) rope_next = __builtin_nontemporal_load(rope_pt + s0 + KB + lane);

    // scores: lane = key within tile, wave = query t; 2 partial sums (ILP)
    const int s = s0 + lane;
    float sc = -INFINITY;
    if (s <= lim) {
      float sumA = rope_cur, sumB = 0.f;
#pragma unroll
      for (int cc = 0; cc < 32; cc += 2) {
        const float4 kv0 = *(const float4*)&kv[cur][lane][(cc ^ (lane & 7)) << 2];
        const float4 kv1 = *(const float4*)&kv[cur][lane][((cc + 1) ^ (lane & 7)) << 2];
        sumA += dot4(kv0, *(const float4*)&qc[t][cc << 2]);
        sumB += dot4(kv1, *(const float4*)&qc[t][(cc + 1) << 2]);
      }
      sc = (sumA + sumB) * 0.07216878364870323f;  // 1/sqrt(192)
    }
    const float mt = wmax(sc);
    const float m_new = fmaxf(m_run, mt);
    const float p = expf(sc - m_new);   // masked: expf(-inf)=0
    const float lt = wsum(p);
    const float f = expf(m_run - m_new);
    l_run = l_run * f + lt;
    accX0 *= f; accX1 *= f; accY0 *= f; accY1 *= f;
    m_run = m_new;

    // PV: lane owns dims (2*lane, 2*lane+1); kk in pairs, 2 indep acc chains
    const int c0 = lane >> 1;
    const int off = (lane & 1) << 1;
    const int pu = __float_as_int(p);
#pragma unroll
    for (int kk = 0; kk < KB; kk += 2) {
      const float pv0 = __int_as_float(__builtin_amdgcn_readlane(pu, kk));
      const float pv1 = __int_as_float(__builtin_amdgcn_readlane(pu, kk + 1));
      const float2 vv0 = *(const float2*)&kv[cur][kk][((c0 ^ (kk & 7)) << 2) + off];
      const float2 vv1 = *(const float2*)&kv[cur][kk + 1][((c0 ^ ((kk + 1) & 7)) << 2) + off];
      accX0 += pv0 * vv0.x;
      accX1 += pv0 * vv0.y;
      accY0 += pv1 * vv1.x;
      accY1 += pv1 * vv1.y;
    }
    __builtin_amdgcn_s_setprio(0);

    // fused copy-out of past rows: LDS -> out_ckv, NON-TEMPORAL stores
#pragma unroll
    for (int u = 0; u < 8; ++u) {
      const int fi = tid + u * 256;
      const int row = fi >> 5;
      const int c   = fi & 31;
      const int ss = s0 + row;
      if (ss < 4092) {
        const vfloat4 v = *(const vfloat4*)&kv[cur][row][(c ^ (row & 7)) << 2];
        __builtin_nontemporal_store(
            v, (vfloat4*)(out_ckv + ((size_t)(b * 4096 + ss)) * 2048 + h * 128 + (c << 2)));
      }
    }

    __builtin_amdgcn_s_barrier();   // all waves done reading kv[cur]
    cur ^= 1;
    rope_cur = rope_next;
  }

  const size_t base = ((size_t)((b * 16 + h) * 4 + t)) * NSPLIT + sp;
  part_acc[base * 128 + (lane << 1)]     = accX0 + accY0;
  part_acc[base * 128 + (lane << 1) + 1] = accX1 + accY1;
  if (lane == 0) {
    part_ml[base * 2]     = m_run;
    part_ml[base * 2 + 1] = l_run;
  }
}

// ---------------- combine split partials -------------------------------------
__global__ __launch_bounds__(128) void combine_kernel(
    const float* __restrict__ part_acc, const float* __restrict__ part_ml,
    float* __restrict__ merged) {
  const int h = blockIdx.x & 15;
  const int b = blockIdx.x >> 4;
  const int d = threadIdx.x;  // 0..127
#pragma unroll
  for (int t = 0; t < 4; ++t) {
    const size_t base = ((size_t)((b * 16 + h) * 4 + t)) * NSPLIT;
    float mm[NSPLIT], ll[NSPLIT];
    float m = -INFINITY;
#pragma unroll
    for (int sp = 0; sp < NSPLIT; ++sp) {
      mm[sp] = part_ml[(base + sp) * 2];
      ll[sp] = part_ml[(base + sp) * 2 + 1];
      m = fmaxf(m, mm[sp]);
    }
    float den = 0.f, num = 0.f;
#pragma unroll
    for (int sp = 0; sp < NSPLIT; ++sp) {
      const float w = expf(mm[sp] - m);
      den += w * ll[sp];
      num += w * part_acc[(base + sp) * 128 + d];
    }
    merged[((size_t)(b * 4 + t)) * 2048 + h * 128 + d] = num / den;
  }
}

// ---------------- output projection (K=2048) ---------------------------------
__global__ __launch_bounds__(256) void outproj_kernel(
    const float* __restrict__ A, const float* __restrict__ W_o,
    float* __restrict__ out0) {
  const int wave = threadIdx.x >> 6;
  const int lane = threadIdx.x & 63;
  const int jbase = (blockIdx.x * 4 + wave) * 2;  // 2048 cols
  const float* w0 = W_o + (size_t)jbase * 2048;
  const float* w1 = w0 + 2048;

  __shared__ float wlds[4][2][2048];  // 64 KB

#pragma unroll
  for (int m = 0; m < 8; ++m) {
    __builtin_amdgcn_global_load_lds(
        (const __attribute__((address_space(1))) void*)(w0 + (m << 8) + (lane << 2)),
        (__attribute__((address_space(3))) void*)&wlds[wave][0][m << 8], 16, 0, AUX_NT);
    __builtin_amdgcn_global_load_lds(
        (const __attribute__((address_space(1))) void*)(w1 + (m << 8) + (lane << 2)),
        (__attribute__((address_space(3))) void*)&wlds[wave][1][m << 8], 16, 0, AUX_NT);
  }
  __syncthreads();

  float acc0[32], acc1[32];
#pragma unroll
  for (int i = 0; i < 32; ++i) { acc0[i] = 0.f; acc1[i] = 0.f; }

#pragma unroll 1
  for (int m = 0; m < 8; ++m) {
    const int k = (lane << 2) + (m << 8);
    const float4 wa = *(const float4*)&wlds[wave][0][k];
    const float4 wb = *(const float4*)&wlds[wave][1][k];
#pragma unroll
    for (int i = 0; i < 32; ++i) {
      const float4 a = *(const float4*)(A + i * 2048 + k);
      acc0[i] += dot4(a, wa);
      acc1[i] += dot4(a, wb);
    }
  }
#pragma unroll
  for (int i = 0; i < 32; ++i) { acc0[i] = wsum(acc0[i]); acc1[i] = wsum(acc1[i]); }
  float myval = 0.f;
#pragma unroll
  for (int i = 0; i < 32; ++i) {
    myval = (lane == i)      ? acc0[i] : myval;
    myval = (lane == i + 32) ? acc1[i] : myval;
  }
  const int mi = lane & 31;
  const int col = jbase + (lane >> 5);
  out0[(size_t)mi * 2048 + col] = myval;
}

extern "C" void kernel_launch(void* const* d_in, const int* in_sizes, int n_in,
                              void* d_out, int out_size, void* d_ws, size_t ws_size,
                              hipStream_t stream) {
  const float* hidden   = (const float*)d_in[0];
  const float* ckv_past = (const float*)d_in[1];
  const float* kr_past  = (const float*)d_in[2];
  // d_in[3] attention_mask: replicated analytically (causal, offset PAST)
  const float* W_dq  = (const float*)d_in[4];
  const float* W_uq  = (const float*)d_in[5];
  const float* W_qr  = (const float*)d_in[6];
  const float* W_dkv = (const float*)d_in[7];
  const float* W_kr  = (const float*)d_in[8];
  const float* W_o   = (const float*)d_in[9];

  float* out0    = (float*)d_out;                       // (8,4,2048)
  float* out_ckv = out0 + (size_t)32 * 2048;            // (8,4096,2048)
  float* out_kr  = out_ckv + (size_t)8 * 4096 * 2048;   // (8,4096,64)

  float* ws       = (float*)d_ws;
  float* ws_cq    = ws;                                  // 32*512
  float* ws_qc    = ws_cq + 32 * 512;                    // 32*2048
  float* ws_qr    = ws_qc + 32 * 2048;                   // 32*1024
  float* part_acc = ws_qr + 32 * 1024;                   // 8*16*4*NSPLIT*128
  float* part_ml  = part_acc + (size_t)8 * 16 * 4 * NSPLIT * 128;
  float* merged   = part_ml + (size_t)8 * 16 * 4 * NSPLIT * 2;   // 32*2048
  float* rope     = merged + 32 * 2048;                  // 8*64*4096 floats

  hipLaunchKernelGGL(proj1_kernel, dim3(328), dim3(256), 0, stream,
                     hidden, W_dq, W_dkv, W_kr, ws_cq, out_ckv, out_kr);
  hipLaunchKernelGGL(proj2_kernel, dim3(384), dim3(256), 0, stream,
                     ws_cq, W_uq, W_qr, ws_qc, ws_qr);
  hipLaunchKernelGGL(rope_kernel, dim3(64, 8), dim3(256), 0, stream,
                     kr_past, out_kr, ws_qr, rope);
  hipLaunchKernelGGL(attn_kernel, dim3(NSPLIT, 16, 8), dim3(256), 0, stream,
                     ckv_past, out_ckv, ws_qc, rope, part_acc, part_ml);
  hipLaunchKernelGGL(combine_kernel, dim3(128), dim3(128), 0, stream,
                     part_acc, part_ml, merged);
  hipLaunchKernelGGL(outproj_kernel, dim3(256), dim3(256), 0, stream,
                     merged, W_o, out0);
}